// Round 4
// baseline (2855.140 us; speedup 1.0000x reference)
//
#include <hip/hip_runtime.h>
#include <math.h>

#define HW2 4096

typedef __attribute__((ext_vector_type(8))) short s16x8;
typedef __attribute__((ext_vector_type(4))) short s16x4;
typedef __attribute__((ext_vector_type(4))) float f32x4;

__device__ __forceinline__ unsigned short f2bf(float x) {
  unsigned int u = __float_as_uint(x);
  u += 0x7fff + ((u >> 16) & 1);          // RNE
  return (unsigned short)(u >> 16);
}

__device__ __forceinline__ void async16(void* lds, const void* g) {
  __builtin_amdgcn_global_load_lds(
      (const __attribute__((address_space(1))) void*)g,
      (__attribute__((address_space(3))) void*)lds, 16, 0, 0);
}

// ---------------------------------------------------------------------------
// fp32 NCHW -> bf16 transposed [b][h][cc][w*32+ci].  Block = (cc, h8, b).
// ---------------------------------------------------------------------------
__global__ __launch_bounds__(256) void tpose_k(
    const float* __restrict__ in, unsigned short* __restrict__ outT, int CC)
{
  __shared__ short sT[32 * 534];
  const int cc = blockIdx.x;
  const int h0 = blockIdx.y * 8;
  const int b  = blockIdx.z;
  const int tid = threadIdx.x;
  const float* ip = in + (size_t)(b * CC + cc) * 32 * 4096;

  for (int e = tid; e < 4096; e += 256) {
    int ci = e >> 7, rem = e & 127;
    int h = rem >> 4, w4 = rem & 15;
    float4 v = *(const float4*)&ip[(size_t)ci * 4096 + (h0 + h) * 64 + w4 * 4];
    short* d = &sT[ci * 534 + h * 66 + w4 * 4];
    d[0] = (short)f2bf(v.x); d[1] = (short)f2bf(v.y);
    d[2] = (short)f2bf(v.z); d[3] = (short)f2bf(v.w);
  }
  __syncthreads();
  unsigned short* ob = outT + (size_t)b * 64 * CC * 2048;
  for (int e = tid; e < 2048; e += 256) {
    int h = e >> 8, rem = e & 255;
    int w = rem >> 2, q = rem & 3;
    s16x8 v;
    #pragma unroll
    for (int j = 0; j < 8; ++j) v[j] = sT[(q * 8 + j) * 534 + h * 66 + w];
    *(s16x8*)&ob[((size_t)(h0 + h) * CC + cc) * 2048 + w * 32 + q * 8] = v;
  }
}

// ---------------------------------------------------------------------------
// Weight prep (coalesced): fp32 OIHW -> bf16 MFMA A-frag order.
// ---------------------------------------------------------------------------
__global__ __launch_bounds__(256) void wprep_k(const float* __restrict__ w,
                                               unsigned short* __restrict__ Wb,
                                               int Cin) {
  __shared__ float sC[32 * 289];
  const int CC = Cin >> 5;
  const int cc = blockIdx.x % CC, cob = blockIdx.x / CC;
  const int tid = threadIdx.x;
  for (int e = tid; e < 2304; e += 256) {
    int co = e / 72, off = e % 72;
    float4 v = *(const float4*)&w[((size_t)(cob * 32 + co) * Cin + cc * 32) * 9 +
                                  off * 4];
    float* d = &sC[co * 289 + off * 4];
    d[0] = v.x; d[1] = v.y; d[2] = v.z; d[3] = v.w;
  }
  __syncthreads();
  unsigned short* ob = Wb + (size_t)(cob * CC + cc) * 9216;
  for (int e = tid; e < 1152; e += 256) {
    int ln = e & 15, q = (e >> 4) & 3, mt = (e >> 6) & 1, t = e >> 7;
    s16x8 v;
    #pragma unroll
    for (int j = 0; j < 8; ++j)
      v[j] = (short)f2bf(sC[(mt * 16 + ln) * 289 + (q * 8 + j) * 9 + t]);
    *(s16x8*)&ob[(size_t)e * 8] = v;
  }
}

// ---------------------------------------------------------------------------
// 3x3 conv + bias + relu via MFMA bf16 implicit GEMM.
// ---------------------------------------------------------------------------
template <int SRC_BF16, int EPI_BF16>
__global__ __launch_bounds__(256, 3) void conv_mfma_k(
    const void* __restrict__ inp,
    const unsigned short* __restrict__ Wb,
    const float* __restrict__ bias,
    void* __restrict__ outp,
    int CC, int occ0, int outCC)
{
  __shared__ short sIn[6 * 66 * 32];   // 25344 B
  __shared__ short sW[9216];           // 18432 B

  const int tid = threadIdx.x;
  const int lane = tid & 63;
  const int wid = tid >> 6;
  const int ln = lane & 15;
  const int q = lane >> 4;
  const int w0 = wid * 16;
  const int pb = blockIdx.x;
  const int b = pb >> 4;
  const int h0 = (pb & 15) * 4;
  const int cob = blockIdx.y;

  if (tid < 48) {
    int r = tid >> 3, side = (tid >> 2) & 1, qq = tid & 3;
    int col = side ? 65 : 0;
    s16x8 z = (s16x8)0;
    *(s16x8*)&sIn[(r * 66 + col) * 32 + qq * 8] = z;
  }
  if (SRC_BF16) {
    #pragma unroll
    for (int r = 0; r < 6; ++r) {
      int h = h0 - 1 + r;
      if (h < 0 || h > 63) {
        s16x8 z = (s16x8)0;
        *(s16x8*)&sIn[(r * 66 + 1) * 32 + tid * 8] = z;
      }
    }
  }

  f32x4 acc[2][4];
  #pragma unroll
  for (int mt = 0; mt < 2; ++mt)
    #pragma unroll
    for (int r = 0; r < 4; ++r) acc[mt][r] = (f32x4){0.f, 0.f, 0.f, 0.f};

  for (int cc = 0; cc < CC; ++cc) {
    {
      const unsigned short* gw = Wb + (size_t)(cob * CC + cc) * 9216;
      for (int s = wid; s < 18; s += 4)
        async16(&sW[s * 512 + lane * 8], gw + s * 512 + lane * 8);
    }
    if (SRC_BF16) {
      const unsigned short* cat = (const unsigned short*)inp;
      #pragma unroll
      for (int k = 0; k < 6; ++k) {
        int h = h0 - 1 + k;
        if (h >= 0 && h <= 63) {
          const unsigned short* gsrc =
              cat + ((size_t)(b * 64 + h) * CC + cc) * 2048 + wid * 512 + lane * 8;
          async16(&sIn[(k * 66 + 1) * 32 + wid * 512 + lane * 8], gsrc);
        }
      }
    } else {
      const float* fin = (const float*)inp;
      const int sq = tid & 3, sw = tid >> 2;
      #pragma unroll
      for (int r = 0; r < 6; ++r) {
        int h = h0 - 1 + r;
        s16x8 v;
        if (h >= 0 && h <= 63) {
          #pragma unroll
          for (int k = 0; k < 8; ++k) {
            float val = fin[((size_t)(b * (CC * 32) + cc * 32 + sq * 8 + k) << 12) +
                            h * 64 + sw];
            v[k] = (short)f2bf(val);
          }
        } else {
          v = (s16x8)0;
        }
        *(s16x8*)&sIn[(r * 66 + sw + 1) * 32 + sq * 8] = v;
      }
    }
    __syncthreads();
    #pragma unroll
    for (int kw = 0; kw < 3; ++kw) {
      s16x8 Bfr[6];
      #pragma unroll
      for (int rp = 0; rp < 6; ++rp)
        Bfr[rp] = *(const s16x8*)&sIn[(rp * 66 + w0 + kw + ln) * 32 + q * 8];
      #pragma unroll
      for (int kh = 0; kh < 3; ++kh) {
        #pragma unroll
        for (int mt = 0; mt < 2; ++mt) {
          s16x8 Afr = *(const s16x8*)&sW[((kh * 3 + kw) * 2 + mt) * 512 + lane * 8];
          #pragma unroll
          for (int r = 0; r < 4; ++r)
            acc[mt][r] = __builtin_amdgcn_mfma_f32_16x16x32_bf16(
                Afr, Bfr[r + kh], acc[mt][r], 0, 0, 0);
        }
      }
    }
    __syncthreads();
  }

  #pragma unroll
  for (int mt = 0; mt < 2; ++mt) {
    const float4 bv = *(const float4*)&bias[cob * 32 + mt * 16 + q * 4];
    #pragma unroll
    for (int r = 0; r < 4; ++r) {
      float y0 = fmaxf(acc[mt][r].x + bv.x, 0.f);
      float y1 = fmaxf(acc[mt][r].y + bv.y, 0.f);
      float y2 = fmaxf(acc[mt][r].z + bv.z, 0.f);
      float y3 = fmaxf(acc[mt][r].w + bv.w, 0.f);
      if (EPI_BF16) {
        s16x4 pk;
        pk[0] = (short)f2bf(y0); pk[1] = (short)f2bf(y1);
        pk[2] = (short)f2bf(y2); pk[3] = (short)f2bf(y3);
        unsigned short* ob = (unsigned short*)outp;
        size_t off = ((size_t)(b * 64 + h0 + r) * outCC + (occ0 + cob)) * 2048 +
                     (w0 + ln) * 32 + mt * 16 + q * 4;
        *(s16x4*)&ob[off] = pk;
      } else {
        float* ob = (float*)outp;
        int co = cob * 32 + mt * 16 + q * 4;
        size_t base = ((size_t)b * outCC + co) * HW2 + (h0 + r) * 64 + w0 + ln;
        ob[base] = y0;
        ob[base + HW2] = y1;
        ob[base + 2 * HW2] = y2;
        ob[base + 3 * HW2] = y3;
      }
    }
  }
}

// ---------------------------------------------------------------------------
// 1x1 head (256->81) + bias + relu + softmax.  Block = (b,h) row, 512 thr.
// Thread (w, cg): co = cg + 8k, k < 11.
// ---------------------------------------------------------------------------
__global__ __launch_bounds__(512) void head_k(
    const float* __restrict__ x2, const float* __restrict__ w3,
    const float* __restrict__ b3, float* __restrict__ kern)
{
  __shared__ float sS[81 * 64];
  const int bh = blockIdx.x;
  const int b = bh >> 6, h = bh & 63;
  const int tid = threadIdx.x;
  const int w = tid & 63, cg = tid >> 6;   // cg 0..7

  float s[11];
  #pragma unroll
  for (int k = 0; k < 11; ++k) {
    int co = cg + 8 * k;
    s[k] = (co < 81) ? b3[co] : 0.f;
  }

  const float* xp = x2 + (size_t)b * 256 * HW2 + h * 64 + w;
  for (int c0 = 0; c0 < 256; c0 += 8) {
    float xv[8];
    #pragma unroll
    for (int j = 0; j < 8; ++j) xv[j] = xp[(size_t)(c0 + j) * HW2];
    #pragma unroll
    for (int k = 0; k < 11; ++k) {
      int co = cg + 8 * k;
      if (co < 81) {
        const float* wp = w3 + co * 256 + c0;
        #pragma unroll
        for (int j = 0; j < 8; ++j) s[k] += xv[j] * wp[j];
      }
    }
  }
  #pragma unroll
  for (int k = 0; k < 11; ++k) {
    int co = cg + 8 * k;
    if (co < 81) sS[co * 64 + w] = fmaxf(s[k], 0.f);
  }
  __syncthreads();
  if (tid < 64) {
    float m = -1e30f;
    for (int c = 0; c < 81; ++c) m = fmaxf(m, sS[c * 64 + tid]);
    float sum = 0.f;
    for (int c = 0; c < 81; ++c) {
      float e = __expf(sS[c * 64 + tid] - m);
      sS[c * 64 + tid] = e;
      sum += e;
    }
    float rr = 1.f / sum;
    for (int c = 0; c < 81; ++c)
      kern[((size_t)(b * 81 + c)) * HW2 + h * 64 + tid] = sS[c * 64 + tid] * rr;
  }
}

// ---------------------------------------------------------------------------
// Spatially-variant conv, software-pipelined: prefetch row i+1's feats while
// computing row i. Block = (b, h, 64-ch chunk); thread = 4 ch x 4 w.
// ---------------------------------------------------------------------------
__global__ __launch_bounds__(256, 3) void svc_k3(
    const float* __restrict__ feats, const float* __restrict__ kern,
    float* __restrict__ out)
{
  __shared__ float sK[81 * 64];
  const int b = blockIdx.z, h = blockIdx.y, cb = blockIdx.x * 64;
  const int tid = threadIdx.x;
  for (int e = tid; e < 81 * 64; e += 256)
    sK[e] = kern[((size_t)(b * 81) + (e >> 6)) * HW2 + h * 64 + (e & 63)];
  __syncthreads();

  const int wq = tid & 15, cs = tid >> 4;
  const int w0 = wq * 4;
  const float* fbase = feats + ((size_t)(b * 1024 + cb + cs * 4)) * HW2;
  const float4 z4 = make_float4(0.f, 0.f, 0.f, 0.f);

  float4 acc[4] = {z4, z4, z4, z4};
  float4 nf[4][3];
  float  f[4][12];

  auto loadrow = [&](int i) {
    int hh = h + i - 4;
    bool v = (hh >= 0) && (hh < 64);     // block-uniform
    int hc = v ? hh : 0;
    #pragma unroll
    for (int ch = 0; ch < 4; ++ch) {
      const float* fp = fbase + (size_t)ch * HW2 + hc * 64;
      nf[ch][0] = (v && wq != 0)  ? *(const float4*)(fp + w0 - 4) : z4;
      nf[ch][1] = v               ? *(const float4*)(fp + w0)     : z4;
      nf[ch][2] = (v && wq != 15) ? *(const float4*)(fp + w0 + 4) : z4;
    }
  };

  loadrow(0);
  #pragma unroll
  for (int i = 0; i < 9; ++i) {
    // unpack row i (waits on its loads), freeing nf for the prefetch
    #pragma unroll
    for (int ch = 0; ch < 4; ++ch) {
      f[ch][0] = nf[ch][0].x; f[ch][1]  = nf[ch][0].y;
      f[ch][2] = nf[ch][0].z; f[ch][3]  = nf[ch][0].w;
      f[ch][4] = nf[ch][1].x; f[ch][5]  = nf[ch][1].y;
      f[ch][6] = nf[ch][1].z; f[ch][7]  = nf[ch][1].w;
      f[ch][8] = nf[ch][2].x; f[ch][9]  = nf[ch][2].y;
      f[ch][10] = nf[ch][2].z; f[ch][11] = nf[ch][2].w;
    }
    if (i < 8) loadrow(i + 1);           // prefetch next row
    #pragma unroll
    for (int j = 0; j < 9; ++j) {
      const float4 kv = *(const float4*)&sK[(i * 9 + j) * 64 + w0];
      #pragma unroll
      for (int ch = 0; ch < 4; ++ch) {
        acc[ch].x += f[ch][j]     * kv.x;
        acc[ch].y += f[ch][j + 1] * kv.y;
        acc[ch].z += f[ch][j + 2] * kv.z;
        acc[ch].w += f[ch][j + 3] * kv.w;
      }
    }
  }
  #pragma unroll
  for (int ch = 0; ch < 4; ++ch)
    *(float4*)&out[((size_t)(b * 1024 + cb + cs * 4 + ch)) * HW2 + h * 64 + w0] =
        acc[ch];
}

// ---------------------------------------------------------------------------
extern "C" void kernel_launch(void* const* d_in, const int* in_sizes, int n_in,
                              void* d_out, int out_size, void* d_ws, size_t ws_size,
                              hipStream_t stream) {
  const float* cur  = (const float*)d_in[0];
  const float* keyl = (const float*)d_in[1];
  const float* keyh = (const float*)d_in[2];
  const float* w_r  = (const float*)d_in[3];
  const float* b_r  = (const float*)d_in[4];
  const float* w2   = (const float*)d_in[5];
  const float* b2   = (const float*)d_in[6];
  const float* w3   = (const float*)d_in[7];
  const float* b3   = (const float*)d_in[8];
  float* out = (float*)d_out;
  char* ws = (char*)d_ws;

  const size_t NEED_FAST = 57409536;
  if (ws_size >= NEED_FAST) {
    unsigned short* cat  = (unsigned short*)ws;
    unsigned short* Wb1  = (unsigned short*)(ws + 16777216);
    unsigned short* Wb2  = (unsigned short*)(ws + 21495808);
    unsigned short* bufA = (unsigned short*)(ws + 23855104);
    float*          x2   = (float*)(ws + 23855104);
    float*          kern = (float*)(ws + 40632320);

    wprep_k<<<256, 256, 0, stream>>>(w_r, Wb1, 1024);
    wprep_k<<<128, 256, 0, stream>>>(w2,  Wb2, 512);

    tpose_k<<<dim3(32, 8, 4), 256, 0, stream>>>(cur, bufA, 32);
    conv_mfma_k<1, 1><<<dim3(64, 8), 256, 0, stream>>>(bufA, Wb1, b_r, cat, 32, 0, 16);
    tpose_k<<<dim3(32, 8, 4), 256, 0, stream>>>(keyl, bufA, 32);
    conv_mfma_k<1, 1><<<dim3(64, 8), 256, 0, stream>>>(bufA, Wb1, b_r, cat, 32, 8, 16);
    conv_mfma_k<1, 0><<<dim3(64, 8), 256, 0, stream>>>(cat, Wb2, b2, x2, 16, 0, 256);

    head_k<<<256, 512, 0, stream>>>(x2, w3, b3, kern);
    svc_k3<<<dim3(16, 64, 4), 256, 0, stream>>>(keyh, kern, out);
  } else {
    unsigned short* cat  = (unsigned short*)ws;
    float*          x2   = (float*)(ws + 16777216);
    float*          kern = (float*)(ws + 33554432);
    unsigned short* Wb1  = (unsigned short*)(ws + 38862848);
    unsigned short* Wb2  = (unsigned short*)(ws + 43581440);

    wprep_k<<<256, 256, 0, stream>>>(w_r, Wb1, 1024);
    wprep_k<<<128, 256, 0, stream>>>(w2,  Wb2, 512);

    conv_mfma_k<0, 1><<<dim3(64, 8), 256, 0, stream>>>(cur,  Wb1, b_r, cat, 32, 0, 16);
    conv_mfma_k<0, 1><<<dim3(64, 8), 256, 0, stream>>>(keyl, Wb1, b_r, cat, 32, 8, 16);
    conv_mfma_k<1, 0><<<dim3(64, 8), 256, 0, stream>>>(cat,  Wb2, b2, x2, 16, 0, 256);

    head_k<<<256, 512, 0, stream>>>(x2, w3, b3, kern);
    svc_k3<<<dim3(16, 64, 4), 256, 0, stream>>>(keyh, kern, out);
  }
}